// Round 1
// baseline (327.594 us; speedup 1.0000x reference)
//
#include <hip/hip_runtime.h>
#include <cstdint>

// Problem constants (from reference): B=16384 rows, C=4096 classes.
#define CLS 4096

static __device__ __forceinline__ float wave_reduce_max(float v) {
    #pragma unroll
    for (int off = 32; off > 0; off >>= 1)
        v = fmaxf(v, __shfl_down(v, off, 64));
    return v;
}
static __device__ __forceinline__ float wave_reduce_sum(float v) {
    #pragma unroll
    for (int off = 32; off > 0; off >>= 1)
        v += __shfl_down(v, off, 64);
    return v;
}

// Zero the winner array (ws is re-poisoned to 0xAA before every launch).
__global__ void init_winner(unsigned long long* __restrict__ winner, int n) {
    int i = blockIdx.x * blockDim.x + threadIdx.x;
    if (i < n) winner[i] = 0ull;
}

// Last-write-wins scatter: temp_v[index[i] % B] = v[index[i]], duplicate pos
// resolved to largest i (numpy fancy-assignment semantics). Encode
// key = (i+1)<<32 | float_bits(value); atomicMax picks max i (i unique, so
// the low-word payload is never compared).
__global__ void scatter_v(const int* __restrict__ index,
                          const float* __restrict__ v,
                          unsigned long long* __restrict__ winner, int n) {
    int i = blockIdx.x * blockDim.x + threadIdx.x;
    if (i >= n) return;
    int idx = index[i];
    int pos = idx % n;
    unsigned int fb = __float_as_uint(v[idx]);
    unsigned long long key =
        ((unsigned long long)(unsigned)(i + 1) << 32) | (unsigned long long)fb;
    atomicMax(&winner[pos], key);
}

// One block per row. Decode temp_v inline; skip rows with zero mask (~68%).
// Row (16 KB) cached in registers: 256 thr x 4 float4 = 16 floats/thread.
__global__ __launch_bounds__(256)
void ce_rows(const float* __restrict__ input,
             const int* __restrict__ target,
             const unsigned long long* __restrict__ winner,
             float* __restrict__ partial) {
    const int row = blockIdx.x;
    const int t = threadIdx.x;
    unsigned long long w = winner[row];
    float val = __uint_as_float((unsigned)(w & 0xFFFFFFFFull));
    if (val == 0.0f) {   // covers both "never written" (w==0) and v-value==0
        if (t == 0) partial[row] = 0.0f;
        return;
    }
    const float4* rp = (const float4*)(input + (size_t)row * CLS);
    float4 x[4];
    #pragma unroll
    for (int j = 0; j < 4; ++j) x[j] = rp[t + 256 * j];

    float m = -INFINITY;
    #pragma unroll
    for (int j = 0; j < 4; ++j)
        m = fmaxf(m, fmaxf(fmaxf(x[j].x, x[j].y), fmaxf(x[j].z, x[j].w)));

    __shared__ float red_m[4];
    __shared__ float red_s[4];
    m = wave_reduce_max(m);
    if ((t & 63) == 0) red_m[t >> 6] = m;
    __syncthreads();
    float bm = fmaxf(fmaxf(red_m[0], red_m[1]), fmaxf(red_m[2], red_m[3]));

    float s = 0.f;
    #pragma unroll
    for (int j = 0; j < 4; ++j)
        s += __expf(x[j].x - bm) + __expf(x[j].y - bm) +
             __expf(x[j].z - bm) + __expf(x[j].w - bm);
    s = wave_reduce_sum(s);
    if ((t & 63) == 0) red_s[t >> 6] = s;
    __syncthreads();

    if (t == 0) {
        float tot = red_s[0] + red_s[1] + red_s[2] + red_s[3];
        float xt = input[(size_t)row * CLS + target[row]];
        float loss = bm + __logf(tot) - xt;   // -log_softmax[target]
        partial[row] = loss * val;
    }
}

__global__ __launch_bounds__(1024)
void reduce_partial(const float* __restrict__ partial,
                    float* __restrict__ out, int n) {
    int t = threadIdx.x;
    float s = 0.f;
    for (int i = t; i < n; i += 1024) s += partial[i];
    s = wave_reduce_sum(s);
    __shared__ float red[16];
    if ((t & 63) == 0) red[t >> 6] = s;
    __syncthreads();
    if (t == 0) {
        float tot = 0.f;
        #pragma unroll
        for (int k = 0; k < 16; ++k) tot += red[k];
        out[0] = tot / (float)n;
    }
}

extern "C" void kernel_launch(void* const* d_in, const int* in_sizes, int n_in,
                              void* d_out, int out_size, void* d_ws, size_t ws_size,
                              hipStream_t stream) {
    const float* input  = (const float*)d_in[0];   // [B, C] fp32
    const float* v      = (const float*)d_in[1];   // [N] fp32
    const int*   target = (const int*)d_in[2];     // [B] int32
    const int*   index  = (const int*)d_in[3];     // [B] int32
    float* out = (float*)d_out;

    const int B = in_sizes[2];                     // 16384

    unsigned long long* winner = (unsigned long long*)d_ws;
    float* partial = (float*)((char*)d_ws + (size_t)B * sizeof(unsigned long long));

    init_winner<<<(B + 255) / 256, 256, 0, stream>>>(winner, B);
    scatter_v<<<(B + 255) / 256, 256, 0, stream>>>(index, v, winner, B);
    ce_rows<<<B, 256, 0, stream>>>(input, target, winner, partial);
    reduce_partial<<<1, 1024, 0, stream>>>(partial, out, B);
}